// Round 13
// baseline (206.902 us; speedup 1.0000x reference)
//
#include <hip/hip_runtime.h>
#include <hip/hip_fp16.h>

#define EPS      1e-7f
#define MAX_TANH 15.0f
#define MAXNORM  0.99999f   // (1 - 1e-5) / sqrt(c), c = 1
#define ART_CLIP 0.99999f   // 1 - 1e-5
#define HGRID    512        // coarse-partition blocks (histogram & scatter)
#define RPB      128        // rows per coarse bucket (row >> 7)
#define CAPF     4096       // fine-pass LDS staging (mean ~3069, huge margin)
#define NBMAX    512

__device__ __forceinline__ float wave_sum64(float v) {
#pragma unroll
    for (int o = 32; o > 0; o >>= 1) v += __shfl_xor(v, o, 64);
    return v;
}

// sum across an aligned 16-lane group
__device__ __forceinline__ float gsum16(float v) {
    v += __shfl_xor(v, 1, 64);
    v += __shfl_xor(v, 2, 64);
    v += __shfl_xor(v, 4, 64);
    v += __shfl_xor(v, 8, 64);
    return v;
}

__device__ __forceinline__ float clamp_tanh_arg(float x) {
    return fminf(fmaxf(x, -MAX_TANH), MAX_TANH);
}

__device__ __forceinline__ float artanh_clip(float x) {
    x = fminf(fmaxf(x, -ART_CLIP), ART_CLIP);
    return 0.5f * logf((1.0f + x) / (1.0f - x));
}

// fma a half4 (as uint2) * m into acc
__device__ __forceinline__ void fma_h4(float4& acc, uint2 u, float m) {
    float2 f01 = __half22float2(*reinterpret_cast<__half2*>(&u.x));
    float2 f23 = __half22float2(*reinterpret_cast<__half2*>(&u.y));
    acc.x = fmaf(f01.x, m, acc.x); acc.y = fmaf(f01.y, m, acc.y);
    acc.z = fmaf(f23.x, m, acc.z); acc.w = fmaf(f23.y, m, acc.w);
}

// ---------------------------------------------------------------------------
// K1 (fat). Blocks [0, HGRID): coarse histogram of row>>7 into LDS, coalesced
// write of per-block counts. Blocks [HGRID, ...): layer-1 transform (fp16):
//   ht = logmap0(proj(mobius_add(proj(mobius_matvec(W,x)), hyp_bias)))
// ---------------------------------------------------------------------------
__global__ __launch_bounds__(256) void hist_transform_kernel(
    const int* __restrict__ rows, int* __restrict__ histB,
    int n_edges, int epb, int nb,
    const float* __restrict__ x, const float* __restrict__ W,
    const float* __restrict__ b, __half* __restrict__ ht, int n_nodes)
{
    __shared__ float WT[64 * 65];
    __shared__ float xs[4][64];
    __shared__ int hh[NBMAX];

    if (blockIdx.x < HGRID) {
        const int b0 = blockIdx.x * epb;
        const int b1 = min(b0 + epb, n_edges);
        for (int j = threadIdx.x; j < nb; j += 256) hh[j] = 0;
        __syncthreads();
        for (int i = b0 + threadIdx.x; i < b1; i += 256)
            atomicAdd(&hh[rows[i] >> 7], 1);
        __syncthreads();
        for (int j = threadIdx.x; j < nb; j += 256)
            histB[blockIdx.x * nb + j] = hh[j];
        return;
    }

    // ---------------- transform half ----------------
    const int t = threadIdx.x;
    const int lane = t & 63;
    const int wv = t >> 6;
    const int bid = blockIdx.x - HGRID;
    const int tgrid = gridDim.x - HGRID;

#pragma unroll
    for (int r = 0; r < 16; ++r) {
        int idx = r * 256 + t;
        WT[(idx & 63) * 65 + (idx >> 6)] = W[idx];
    }
    __syncthreads();

    // hyp_bias = proj(expmap0(b)); |expmap0(b)| = tanh(|b|)
    float bj = b[lane];
    float bn = fmaxf(sqrtf(wave_sum64(bj * bj)), EPS);
    float tb = tanhf(clamp_tanh_arg(bn));
    float hb = tb * bj / bn;
    if (tb > MAXNORM) { hb *= MAXNORM / tb; tb = MAXNORM; }
    const float y2 = tb * tb;

    for (long long base = (long long)bid * 4; base < n_nodes;
         base += (long long)tgrid * 4) {
        long long node = base + wv;
        float xj = 0.0f;
        if (node < n_nodes) xj = x[node * 64 + lane];
        xs[wv][lane] = xj;

        float mxj = 0.0f;
#pragma unroll
        for (int k = 0; k < 64; ++k)
            mxj = fmaf(xs[wv][k], WT[k * 65 + lane], mxj);

        float xn  = fmaxf(sqrtf(wave_sum64(xj * xj)), EPS);
        float mxn = fmaxf(sqrtf(wave_sum64(mxj * mxj)), EPS);
        float r = tanhf(clamp_tanh_arg(mxn / xn * artanh_clip(xn)));  // = |h|
        float hj = r * mxj / mxn;
        float hn = fmaxf(r, EPS);
        if (hn > MAXNORM) { hj *= MAXNORM / hn; hn = MAXNORM; }

        float x2 = hn * hn;
        float xy = wave_sum64(hj * hb);
        float num = (1.0f + 2.0f * xy + y2) * hj + (1.0f - x2) * hb;
        float den = fmaxf(1.0f + 2.0f * xy + x2 * y2, EPS);
        hj = num / den;

        float hn2 = fmaxf(sqrtf(wave_sum64(hj * hj)), EPS);
        if (hn2 > MAXNORM) { hj *= MAXNORM / hn2; hn2 = MAXNORM; }

        float htj = artanh_clip(hn2) * hj / hn2;   // logmap0

        if (node < n_nodes) ht[node * 64 + lane] = __float2half(htj);
    }
}

// ---------------------------------------------------------------------------
// K2a: one block per coarse bucket; scan its HGRID per-block counts in place
// into within-bucket exclusive offsets; write bucket total.
// ---------------------------------------------------------------------------
__global__ __launch_bounds__(HGRID) void scan_bucket_kernel(
    int* __restrict__ histB, int* __restrict__ tot, int nb)
{
    __shared__ int wsum[8];
    const int b = blockIdx.x;
    const int t = threadIdx.x;
    const int lane = t & 63, wid = t >> 6;
    int v = histB[t * nb + b];
    int incl = v;
#pragma unroll
    for (int o = 1; o < 64; o <<= 1) {
        int tt = __shfl_up(incl, o, 64);
        if (lane >= o) incl += tt;
    }
    if (lane == 63) wsum[wid] = incl;
    __syncthreads();
    if (wid == 0 && lane < 8) {
        int ws = wsum[lane];
#pragma unroll
        for (int o = 1; o < 8; o <<= 1) {
            int tt = __shfl_up(ws, o, 64);
            if (lane >= o) ws += tt;
        }
        wsum[lane] = ws;
    }
    __syncthreads();
    int base = (wid > 0) ? wsum[wid - 1] : 0;
    histB[t * nb + b] = base + incl - v;
    if (t == HGRID - 1) tot[b] = base + incl;
}

// ---------------------------------------------------------------------------
// K3: coarse scatter via LDS cursors (no global atomics). Each block first
// re-derives bucket_base locally from tot (512-wide LDS Hillis-Steele —
// folds the old base-scan kernel in); block 0 also writes it to global for
// K4. cursor = bucket base + within-bucket per-block offset.
// Record: x=(row<<16)|col, y=mask.
// ---------------------------------------------------------------------------
__global__ __launch_bounds__(512) void coarse_scatter_kernel(
    const int* __restrict__ rows, const int* __restrict__ cols,
    const float* __restrict__ edge_mask, const int* __restrict__ off,
    const int* __restrict__ tot, int* __restrict__ bucket_base,
    int2* __restrict__ coarse, int n_edges, int epb, int nb)
{
    __shared__ int s[NBMAX];
    __shared__ int cur[NBMAX];
    const int t = threadIdx.x;

    // local base scan over bucket totals
    int v = (t < nb) ? tot[t] : 0;
    s[t] = v;
    __syncthreads();
    for (int o = 1; o < NBMAX; o <<= 1) {
        int u = (t >= o) ? s[t - o] : 0;
        __syncthreads();
        s[t] += u;
        __syncthreads();
    }
    int base = s[t] - v;                     // exclusive prefix
    if (blockIdx.x == 0) {
        if (t < nb) bucket_base[t] = base;
        if (t == nb - 1) bucket_base[nb] = s[t];
    }
    if (t < nb) cur[t] = base + off[blockIdx.x * nb + t];
    __syncthreads();

    const int b0 = blockIdx.x * epb;
    const int b1 = min(b0 + epb, n_edges);
    for (int i = b0 + t; i < b1; i += 512) {
        int r = rows[i], c = cols[i];
        float m = edge_mask[i];
        int pos = atomicAdd(&cur[r >> 7], 1);
        coarse[pos] = make_int2((r << 16) | c, __float_as_int(m));
    }
}

// ---------------------------------------------------------------------------
// K4 fused: fine partition + layer-1 gather/finish + layer-2 HypLinear.
// One block per coarse bucket (~3069 edges, 128 rows):
//   LDS hist -> LDS scan -> LDS scatter (sorted edges stay IN LDS)
//   -> packed csr4 write-out (col | fp16 mask) + row_start for layer 2
//   -> gather straight from LDS edge records (random global ht1 reads)
//   -> finish -> fused HypLinear(W1,b1) + logmap0 -> ht2 (fp16).
// ---------------------------------------------------------------------------
__global__ __launch_bounds__(1024) void fine_gather_kernel(
    const int2* __restrict__ coarse, const int* __restrict__ bucket_base,
    const __half* __restrict__ ht1, const float* __restrict__ node_mask,
    const float* __restrict__ W, const float* __restrict__ bvec,
    unsigned* __restrict__ csr4, int* __restrict__ row_start,
    __half* __restrict__ ht2, int n_nodes, int n_edges)
{
    __shared__ int hh[RPB], incl[RPB], curs[RPB];
    __shared__ int2 outE[CAPF];                // 32 KB
    __shared__ float WT[4096];                 // 16 KB, xor-swizzled W^T
    __shared__ float xs[64 * 68];              // 17 KB, matvec round-trip

    const int t = threadIdx.x;
    const int b = blockIdx.x;
    const int q = t & 15;                      // dim quad: dims 4q..4q+3
    const int g = t >> 4;                      // node group 0..63
    const int bbase = bucket_base[b];
    const int n_e = bucket_base[b + 1] - bbase;

    // stage W^T (xor-swizzled for conflict-free float4 reads) + hyp_bias
#pragma unroll
    for (int r = 0; r < 4; ++r) {
        int idx = r * 1024 + t;
        int j = idx >> 6, k = idx & 63;
        WT[(k << 6) | (j ^ ((k & 15) << 2))] = W[idx];
    }
    float4 b4 = ((const float4*)bvec)[q];
    float ssb = b4.x*b4.x + b4.y*b4.y + b4.z*b4.z + b4.w*b4.w;
    float bn = fmaxf(sqrtf(gsum16(ssb)), EPS);
    float tb = tanhf(clamp_tanh_arg(bn));
    float sb = tb / bn;
    float4 hb4 = make_float4(b4.x * sb, b4.y * sb, b4.z * sb, b4.w * sb);
    if (tb > MAXNORM) {
        float sc = MAXNORM / tb;
        hb4.x *= sc; hb4.y *= sc; hb4.z *= sc; hb4.w *= sc;
        tb = MAXNORM;
    }
    const float y2 = tb * tb;

    // ---- fine partition into LDS ----
    if (t < RPB) hh[t] = 0;
    __syncthreads();
    for (int i = t; i < n_e; i += 1024)
        atomicAdd(&hh[(coarse[bbase + i].x >> 16) & (RPB - 1)], 1);
    __syncthreads();
    if (t < RPB) incl[t] = hh[t];
    __syncthreads();
    for (int off = 1; off < RPB; off <<= 1) {
        int v = (t < RPB && t >= off) ? incl[t - off] : 0;
        __syncthreads();
        if (t < RPB) incl[t] += v;
        __syncthreads();
    }
    if (t < RPB) {
        curs[t] = incl[t] - hh[t];
        int grow = (b << 7) + t;
        if (grow < n_nodes) row_start[grow] = bbase + incl[t] - hh[t];
    }
    if (b == gridDim.x - 1 && t == 0) row_start[n_nodes] = n_edges;
    __syncthreads();
    for (int i = t; i < n_e; i += 1024) {
        int2 rec = coarse[bbase + i];
        int slot = atomicAdd(&curs[(rec.x >> 16) & (RPB - 1)], 1);
        if (slot < CAPF) outE[slot] = make_int2(rec.x & 0xffff, rec.y);
    }
    __syncthreads();

    // ---- packed csr for layer 2 (coalesced) ----
    const int lim = min(n_e, CAPF);
    for (int i = t; i < lim; i += 1024) {
        int2 rec = outE[i];
        __half hm = __float2half(__int_as_float(rec.y));
        csr4[bbase + i] = (unsigned)rec.x |
                          ((unsigned)*reinterpret_cast<unsigned short*>(&hm) << 16);
    }

    // ---- gather + finish + HypLinear for this bucket's 128 nodes ----
#pragma unroll
    for (int batch = 0; batch < 2; ++batch) {
        const int ln = batch * 64 + g;               // local row 0..127
        const int node = (b << 7) + ln;
        const bool valid = node < n_nodes;
        const int nd = valid ? node : (n_nodes - 1);
        const int s0 = incl[ln] - hh[ln];
        const int e0 = incl[ln];

        float4 acc = make_float4(0.f, 0.f, 0.f, 0.f);
        float msum = 0.f;
        int j = s0;
        for (; j + 8 <= e0; j += 8) {               // 8 loads in flight
            int2 rr[8];
#pragma unroll
            for (int k = 0; k < 8; ++k) rr[k] = outE[j + k];
            uint2 uu[8];
#pragma unroll
            for (int k = 0; k < 8; ++k)
                uu[k] = *((const uint2*)(ht1 + (long long)rr[k].x * 64) + q);
#pragma unroll
            for (int k = 0; k < 8; ++k) {
                float m = __int_as_float(rr[k].y);
                fma_h4(acc, uu[k], m);
                msum += m;
            }
        }
        for (; j < e0; ++j) {
            int2 rec = outE[j];
            uint2 u = *((const uint2*)(ht1 + (long long)rec.x * 64) + q);
            float m = __int_as_float(rec.y);
            fma_h4(acc, u, m);
            msum += m;
        }

        const float inv = 1.0f / fmaxf(msum, 1.0f);
        acc.x *= inv; acc.y *= inv; acc.z *= inv; acc.w *= inv;

        // finish: proj(expmap0(relu(logmap0(proj(expmap0(agg)))))) * nm
        float ss = acc.x*acc.x + acc.y*acc.y + acc.z*acc.z + acc.w*acc.w;
        float n1 = fmaxf(sqrtf(gsum16(ss)), EPS);
        float t1 = tanhf(clamp_tanh_arg(n1));
        float r1 = t1 / n1;
        acc.x *= r1; acc.y *= r1; acc.z *= r1; acc.w *= r1;
        if (t1 > MAXNORM) {
            float sc = MAXNORM / t1;
            acc.x *= sc; acc.y *= sc; acc.z *= sc; acc.w *= sc;
            t1 = MAXNORM;
        }
        float n2 = fmaxf(t1, EPS);
        float r2s = artanh_clip(n2) / n2;
        acc.x = fmaxf(acc.x * r2s, 0.f); acc.y = fmaxf(acc.y * r2s, 0.f);
        acc.z = fmaxf(acc.z * r2s, 0.f); acc.w = fmaxf(acc.w * r2s, 0.f);

        ss = acc.x*acc.x + acc.y*acc.y + acc.z*acc.z + acc.w*acc.w;
        float n3 = fmaxf(sqrtf(gsum16(ss)), EPS);
        float t3 = tanhf(clamp_tanh_arg(n3));
        float r3 = t3 / n3;
        acc.x *= r3; acc.y *= r3; acc.z *= r3; acc.w *= r3;
        if (t3 > MAXNORM) {
            float sc = MAXNORM / t3;
            acc.x *= sc; acc.y *= sc; acc.z *= sc; acc.w *= sc;
            t3 = MAXNORM;
        }

        const float nm = node_mask[nd];
        acc.x *= nm; acc.y *= nm; acc.z *= nm; acc.w *= nm;

        // fused next-layer HypLinear + logmap0 -> ht2 (fp16)
        float* xrow = &xs[g * 68];                  // group-private row
        *(float4*)(xrow + (q << 2)) = acc;          // in-wave LDS ordering ok

        float4 mx = make_float4(0.f, 0.f, 0.f, 0.f);
#pragma unroll
        for (int k = 0; k < 64; ++k) {
            float xk = xrow[k];
            const float4 w4 = *(const float4*)&WT[(k << 6) | ((q << 2) ^ ((k & 15) << 2))];
            mx.x = fmaf(w4.x, xk, mx.x); mx.y = fmaf(w4.y, xk, mx.y);
            mx.z = fmaf(w4.z, xk, mx.z); mx.w = fmaf(w4.w, xk, mx.w);
        }

        float xn  = fmaxf(t3 * fabsf(nm), EPS);     // |x| known analytically
        float ssm = mx.x*mx.x + mx.y*mx.y + mx.z*mx.z + mx.w*mx.w;
        float mxn = fmaxf(sqrtf(gsum16(ssm)), EPS);
        float r = tanhf(clamp_tanh_arg(mxn / xn * artanh_clip(xn)));
        float rs = r / mxn;
        float4 hj = make_float4(mx.x * rs, mx.y * rs, mx.z * rs, mx.w * rs);
        float hn = fmaxf(r, EPS);
        if (hn > MAXNORM) {
            float sc = MAXNORM / hn;
            hj.x *= sc; hj.y *= sc; hj.z *= sc; hj.w *= sc;
            hn = MAXNORM;
        }

        float x2 = hn * hn;
        float xy = gsum16(hj.x*hb4.x + hj.y*hb4.y + hj.z*hb4.z + hj.w*hb4.w);
        float ca = 1.0f + 2.0f * xy + y2;
        float cb = 1.0f - x2;
        float iden = 1.0f / fmaxf(1.0f + 2.0f * xy + x2 * y2, EPS);
        hj.x = (ca * hj.x + cb * hb4.x) * iden;
        hj.y = (ca * hj.y + cb * hb4.y) * iden;
        hj.z = (ca * hj.z + cb * hb4.z) * iden;
        hj.w = (ca * hj.w + cb * hb4.w) * iden;

        float ssh = hj.x*hj.x + hj.y*hj.y + hj.z*hj.z + hj.w*hj.w;
        float hn2 = fmaxf(sqrtf(gsum16(ssh)), EPS);
        float sc2 = (hn2 > MAXNORM) ? (MAXNORM / hn2) : 1.0f;
        float hnc = fminf(hn2, MAXNORM);
        float lr = artanh_clip(hnc) / hnc * sc2;    // logmap0 incl. proj scale
        hj.x *= lr; hj.y *= lr; hj.z *= lr; hj.w *= lr;

        if (valid) {
            __half2 p01 = __float22half2_rn(make_float2(hj.x, hj.y));
            __half2 p23 = __float22half2_rn(make_float2(hj.z, hj.w));
            uint2 o;
            o.x = *reinterpret_cast<unsigned*>(&p01);
            o.y = *reinterpret_cast<unsigned*>(&p23);
            *((uint2*)(ht2 + (long long)node * 64) + q) = o;
        }
    }
}

// ---------------------------------------------------------------------------
// G2: layer-2 gather + finish -> fp32 output. 4 nodes/wave, 16 lanes/node,
// packed 4 B csr records (col | fp16 mask), 8 loads in flight per lane.
// ---------------------------------------------------------------------------
__global__ __launch_bounds__(256) void gather2_kernel(
    const __half* __restrict__ ht, const unsigned* __restrict__ csr4,
    const int* __restrict__ row_start, const float* __restrict__ node_mask,
    float* __restrict__ outp, int n_nodes)
{
    const int t = threadIdx.x;
    const int lane = t & 63;
    const int wv = t >> 6;
    const int ns = lane >> 4;
    const int q  = lane & 15;

    const int node = blockIdx.x * 16 + (wv << 2) + ns;
    const bool valid = node < n_nodes;
    const int nd = valid ? node : (n_nodes - 1);
    const int s = row_start[nd];
    const int e = row_start[nd + 1];

    float4 acc = make_float4(0.f, 0.f, 0.f, 0.f);
    float msum = 0.f;
    int j = s;
    for (; j + 8 <= e; j += 8) {
        unsigned vv[8];
#pragma unroll
        for (int k = 0; k < 8; ++k) vv[k] = csr4[j + k];
        uint2 uu[8];
#pragma unroll
        for (int k = 0; k < 8; ++k)
            uu[k] = *((const uint2*)(ht + (long long)(vv[k] & 0xffffu) * 64) + q);
#pragma unroll
        for (int k = 0; k < 8; ++k) {
            unsigned short hbits = vv[k] >> 16;
            float m = __half2float(*reinterpret_cast<__half*>(&hbits));
            fma_h4(acc, uu[k], m);
            msum += m;
        }
    }
    for (; j < e; ++j) {
        unsigned v = csr4[j];
        uint2 u = *((const uint2*)(ht + (long long)(v & 0xffffu) * 64) + q);
        unsigned short hbits = v >> 16;
        float m = __half2float(*reinterpret_cast<__half*>(&hbits));
        fma_h4(acc, u, m);
        msum += m;
    }

    const float inv = 1.0f / fmaxf(msum, 1.0f);
    acc.x *= inv; acc.y *= inv; acc.z *= inv; acc.w *= inv;

    float ss = acc.x*acc.x + acc.y*acc.y + acc.z*acc.z + acc.w*acc.w;
    float n1 = fmaxf(sqrtf(gsum16(ss)), EPS);
    float t1 = tanhf(clamp_tanh_arg(n1));
    float r1 = t1 / n1;
    acc.x *= r1; acc.y *= r1; acc.z *= r1; acc.w *= r1;
    if (t1 > MAXNORM) {
        float sc = MAXNORM / t1;
        acc.x *= sc; acc.y *= sc; acc.z *= sc; acc.w *= sc;
        t1 = MAXNORM;
    }
    float n2 = fmaxf(t1, EPS);
    float r2 = artanh_clip(n2) / n2;
    acc.x = fmaxf(acc.x * r2, 0.f); acc.y = fmaxf(acc.y * r2, 0.f);
    acc.z = fmaxf(acc.z * r2, 0.f); acc.w = fmaxf(acc.w * r2, 0.f);

    ss = acc.x*acc.x + acc.y*acc.y + acc.z*acc.z + acc.w*acc.w;
    float n3 = fmaxf(sqrtf(gsum16(ss)), EPS);
    float t3 = tanhf(clamp_tanh_arg(n3));
    float r3 = t3 / n3;
    acc.x *= r3; acc.y *= r3; acc.z *= r3; acc.w *= r3;
    if (t3 > MAXNORM) {
        float sc = MAXNORM / t3;
        acc.x *= sc; acc.y *= sc; acc.z *= sc; acc.w *= sc;
        t3 = MAXNORM;
    }

    const float nm = node_mask[nd];
    acc.x *= nm; acc.y *= nm; acc.z *= nm; acc.w *= nm;

    if (valid) ((float4*)(outp + (long long)node * 64))[q] = acc;
}

extern "C" void kernel_launch(void* const* d_in, const int* in_sizes, int n_in,
                              void* d_out, int out_size, void* d_ws, size_t ws_size,
                              hipStream_t stream) {
    const float* h         = (const float*)d_in[0];
    // d_in[1] = distances (unused by the reference computation)
    const int*   edges     = (const int*)d_in[2];     // [2, E] int32
    const float* node_mask = (const float*)d_in[3];
    const float* edge_mask = (const float*)d_in[4];
    const float* W0        = (const float*)d_in[5];
    const float* b0        = (const float*)d_in[6];
    const float* W1        = (const float*)d_in[7];
    const float* b1        = (const float*)d_in[8];
    float* out = (float*)d_out;

    const int N = in_sizes[0] / 64;
    const int E = in_sizes[4];          // edge_mask is [E,1]
    const int* rows = edges;
    const int* cols = edges + E;

    const int NB  = (N + RPB - 1) / RPB;     // 391 coarse buckets
    const int EPB = (E + HGRID - 1) / HGRID;

    size_t nd = (size_t)N * 64;
    char* ws = (char*)d_ws;
    __half*   B1          = (__half*)ws;   ws += nd * sizeof(__half);   // ht1
    __half*   B2          = (__half*)ws;   ws += nd * sizeof(__half);   // ht2
    int2*     coarse      = (int2*)ws;     ws += (size_t)E * sizeof(int2);
    unsigned* csr4        = (unsigned*)ws; ws += (size_t)E * sizeof(unsigned);
    int*      histB       = (int*)ws;      ws += (size_t)HGRID * NB * sizeof(int);
    int*      tot         = (int*)ws;      ws += (size_t)NB * sizeof(int);
    int*      bucket_base = (int*)ws;      ws += (size_t)(NB + 1) * sizeof(int);
    int*      row_start   = (int*)ws;      ws += (size_t)(N + 1) * sizeof(int);

    const int TGRID = 1024;
    const int NGRID = (N + 15) / 16;

    // K1: coarse histogram + layer-1 transform (fp16 ht1)
    hist_transform_kernel<<<HGRID + TGRID, 256, 0, stream>>>(
        rows, histB, E, EPB, NB, h, W0, b0, B1, N);

    // K2a: per-bucket scan of per-block counts (parallel over buckets)
    scan_bucket_kernel<<<NB, HGRID, 0, stream>>>(histB, tot, NB);

    // K3: local base-scan + coarse scatter (LDS cursors, contiguous chunks)
    coarse_scatter_kernel<<<HGRID, 512, 0, stream>>>(
        rows, cols, edge_mask, histB, tot, bucket_base, coarse, E, EPB, NB);

    // K4 fused: fine partition + layer-1 gather/finish + layer-2 HypLinear
    //           -> ht2 (fp16) + packed csr4 + row_start
    fine_gather_kernel<<<NB, 1024, 0, stream>>>(
        coarse, bucket_base, B1, node_mask, W1, b1, csr4, row_start, B2, N, E);

    // G2: layer-2 gather + finish -> fp32 output
    gather2_kernel<<<NGRID, 256, 0, stream>>>(
        B2, csr4, row_start, node_mask, out, N);
}